// Round 1
// baseline (9584.566 us; speedup 1.0000x reference)
//
#include <hip/hip_runtime.h>

#define SL    48   // sequence length
#define OBS   64   // observation dim
#define HID   84   // hidden dim
#define BATCH 32

#define HID4 (HID/4)   // 21
#define OBS4 (OBS/4)   // 16

// ---------------------------------------------------------------------------
// Phase 1: Riccati sweep (batch-independent). Single block.
// Produces per step: K_i (HID x OBS) and W_i = S_i^{-1} (OBS x OBS).
// Kalman filter with Q = I, R = 0, P_pred_0 = I.
// ---------------------------------------------------------------------------
__global__ __launch_bounds__(512)
void riccati_kernel(const float* __restrict__ Ag,   // HID x HID
                    const float* __restrict__ Cg,   // OBS x HID
                    float* __restrict__ Kg,         // SL * HID * OBS
                    float* __restrict__ Wg,         // SL * OBS * OBS
                    float* __restrict__ Tg,         // HID * OBS scratch (T = P C^T)
                    float* __restrict__ Tt,         // OBS * HID scratch (T^T)
                    float* __restrict__ Ug)         // HID * HID scratch (A * PF)
{
    __shared__ __align__(16) float sP[HID*HID];   // predicted covariance
    __shared__ __align__(16) float sS[OBS*OBS];   // innovation cov -> inverse
    __shared__ float scol[OBS];
    __shared__ float srow[OBS];

    const int t  = threadIdx.x;
    const int nt = blockDim.x;

    // P = I
    for (int idx = t; idx < HID*HID; idx += nt)
        sP[idx] = (idx / HID == idx % HID) ? 1.0f : 0.0f;
    __syncthreads();

    for (int step = 0; step < SL; ++step) {
        // ---- T = P * C^T  (HID x OBS); also write T^T
        for (int idx = t; idx < HID*OBS; idx += nt) {
            const int i = idx / OBS, j = idx % OBS;
            const float4* Pi = reinterpret_cast<const float4*>(&sP[i*HID]);
            const float4* Cj = reinterpret_cast<const float4*>(&Cg[j*HID]);
            float acc = 0.0f;
            #pragma unroll
            for (int k = 0; k < HID4; ++k) {
                const float4 a = Pi[k];
                const float4 b = Cj[k];
                acc += a.x*b.x + a.y*b.y + a.z*b.z + a.w*b.w;
            }
            Tg[i*OBS + j] = acc;
            Tt[j*HID + i] = acc;
        }
        __syncthreads();

        // ---- S = C * T  (OBS x OBS)
        for (int idx4 = t; idx4 < OBS*OBS4; idx4 += nt) {
            const int i = idx4 / OBS4, j4 = idx4 % OBS4;
            float ax = 0.f, ay = 0.f, az = 0.f, aw = 0.f;
            for (int k = 0; k < HID; ++k) {
                const float c = Cg[i*HID + k];
                const float4 tv = *reinterpret_cast<const float4*>(&Tg[k*OBS + j4*4]);
                ax += c*tv.x; ay += c*tv.y; az += c*tv.z; aw += c*tv.w;
            }
            float4 r; r.x = ax; r.y = ay; r.z = az; r.w = aw;
            *reinterpret_cast<float4*>(&sS[i*OBS + j4*4]) = r;
        }
        __syncthreads();

        // ---- in-place Gauss-Jordan inversion of sS (SPD, no pivoting)
        for (int p = 0; p < OBS; ++p) {
            if (t < OBS) {
                scol[t] = sS[t*OBS + p];   // pre-pivot column p
                srow[t] = sS[p*OBS + t];   // pre-pivot row p
            }
            __syncthreads();
            const float piv = 1.0f / srow[p];
            for (int idx = t; idx < OBS*OBS; idx += nt) {
                const int i = idx / OBS, j = idx % OBS;
                float v;
                if (i == p) {
                    v = (j == p) ? piv : srow[j] * piv;
                } else {
                    const float f = scol[i] * piv;
                    v = (j == p) ? -f : sS[idx] - f * srow[j];
                }
                sS[idx] = v;
            }
            __syncthreads();
        }

        // ---- store W = S^{-1}; K = T * W
        float* Wstep = Wg + step*OBS*OBS;
        for (int idx = t; idx < OBS*OBS; idx += nt)
            Wstep[idx] = sS[idx];
        float* Kstep = Kg + step*HID*OBS;
        for (int idx4 = t; idx4 < HID*OBS4; idx4 += nt) {
            const int i = idx4 / OBS4, j4 = idx4 % OBS4;
            float ax = 0.f, ay = 0.f, az = 0.f, aw = 0.f;
            const float* Ti = &Tg[i*OBS];
            for (int k = 0; k < OBS; ++k) {
                const float tv = Ti[k];
                const float4 wv = *reinterpret_cast<const float4*>(&sS[k*OBS + j4*4]);
                ax += tv*wv.x; ay += tv*wv.y; az += tv*wv.z; aw += tv*wv.w;
            }
            float4 r; r.x = ax; r.y = ay; r.z = az; r.w = aw;
            *reinterpret_cast<float4*>(&Kstep[i*OBS + j4*4]) = r;
        }
        __syncthreads();

        // ---- PF = P - K * T^T  (in place on sP)
        for (int idx4 = t; idx4 < HID*HID4; idx4 += nt) {
            const int i = idx4 / HID4, j4 = idx4 % HID4;
            float ax = 0.f, ay = 0.f, az = 0.f, aw = 0.f;
            const float* Ki = &Kstep[i*OBS];
            for (int k = 0; k < OBS; ++k) {
                const float kv = Ki[k];
                const float4 tv = *reinterpret_cast<const float4*>(&Tt[k*HID + j4*4]);
                ax += kv*tv.x; ay += kv*tv.y; az += kv*tv.z; aw += kv*tv.w;
            }
            float4* pp = reinterpret_cast<float4*>(&sP[i*HID + j4*4]);
            float4 pv = *pp;
            pv.x -= ax; pv.y -= ay; pv.z -= az; pv.w -= aw;
            *pp = pv;
        }
        __syncthreads();

        // ---- U = A * PF
        for (int idx4 = t; idx4 < HID*HID4; idx4 += nt) {
            const int i = idx4 / HID4, j4 = idx4 % HID4;
            float ax = 0.f, ay = 0.f, az = 0.f, aw = 0.f;
            const float* Ai = &Ag[i*HID];
            for (int k = 0; k < HID; ++k) {
                const float av = Ai[k];
                const float4 pv = *reinterpret_cast<const float4*>(&sP[k*HID + j4*4]);
                ax += av*pv.x; ay += av*pv.y; az += av*pv.z; aw += av*pv.w;
            }
            float4 r; r.x = ax; r.y = ay; r.z = az; r.w = aw;
            *reinterpret_cast<float4*>(&Ug[i*HID + j4*4]) = r;
        }
        __syncthreads();

        // ---- P = U * A^T + I
        for (int idx = t; idx < HID*HID; idx += nt) {
            const int i = idx / HID, j = idx % HID;
            const float4* Uy = reinterpret_cast<const float4*>(&Ug[i*HID]);
            const float4* Aj = reinterpret_cast<const float4*>(&Ag[j*HID]);
            float acc = (i == j) ? 1.0f : 0.0f;
            #pragma unroll
            for (int k = 0; k < HID4; ++k) {
                const float4 a = Uy[k];
                const float4 b = Aj[k];
                acc += a.x*b.x + a.y*b.y + a.z*b.z + a.w*b.w;
            }
            sP[idx] = acc;
        }
        __syncthreads();

        // ---- symmetrize P (fp drift insurance); pair (i,j)/(j,i) owned by one thread
        for (int idx = t; idx < HID*HID; idx += nt) {
            const int i = idx / HID, j = idx % HID;
            if (i < j) {
                const float v = 0.5f * (sP[i*HID + j] + sP[j*HID + i]);
                sP[i*HID + j] = v;
                sP[j*HID + i] = v;
            }
        }
        __syncthreads();
    }
}

// ---------------------------------------------------------------------------
// Phase 2: per-batch Kalman mean sweep, accumulate q_b = sum_i e_i^T W_i e_i
// ---------------------------------------------------------------------------
__global__ __launch_bounds__(128)
void sweep_kernel(const float* __restrict__ Y,    // BATCH x (SL*OBS)
                  const float* __restrict__ Ag,
                  const float* __restrict__ Cg,
                  const float* __restrict__ Kg,
                  const float* __restrict__ Wg,
                  float* __restrict__ partials)   // BATCH
{
    __shared__ __align__(16) float sx[HID];
    __shared__ __align__(16) float se[OBS];
    __shared__ __align__(16) float sxf[HID];
    __shared__ float qacc[OBS];

    const int b = blockIdx.x;
    const int t = threadIdx.x;
    const float* y = &Y[b * SL * OBS];

    if (t < HID) sx[t] = 0.0f;
    if (t < OBS) qacc[t] = 0.0f;
    __syncthreads();

    for (int i = 0; i < SL; ++i) {
        // e = y_i - C x
        if (t < OBS) {
            const float4* Ct = reinterpret_cast<const float4*>(&Cg[t*HID]);
            const float4* xv = reinterpret_cast<const float4*>(sx);
            float acc = 0.0f;
            #pragma unroll
            for (int k = 0; k < HID4; ++k) {
                const float4 a = Ct[k], v = xv[k];
                acc += a.x*v.x + a.y*v.y + a.z*v.z + a.w*v.w;
            }
            se[t] = y[i*OBS + t] - acc;
        }
        __syncthreads();
        // q += e^T W e   and   xf = x + K e
        if (t < OBS) {
            const float4* Wr = reinterpret_cast<const float4*>(&Wg[i*OBS*OBS + t*OBS]);
            const float4* ev = reinterpret_cast<const float4*>(se);
            float acc = 0.0f;
            #pragma unroll
            for (int k = 0; k < OBS4; ++k) {
                const float4 a = Wr[k], v = ev[k];
                acc += a.x*v.x + a.y*v.y + a.z*v.z + a.w*v.w;
            }
            qacc[t] += se[t] * acc;
        }
        if (t < HID) {
            const float4* Kr = reinterpret_cast<const float4*>(&Kg[i*HID*OBS + t*OBS]);
            const float4* ev = reinterpret_cast<const float4*>(se);
            float acc = 0.0f;
            #pragma unroll
            for (int k = 0; k < OBS4; ++k) {
                const float4 a = Kr[k], v = ev[k];
                acc += a.x*v.x + a.y*v.y + a.z*v.z + a.w*v.w;
            }
            sxf[t] = sx[t] + acc;
        }
        __syncthreads();
        // x = A xf
        if (t < HID) {
            const float4* Ar = reinterpret_cast<const float4*>(&Ag[t*HID]);
            const float4* xf = reinterpret_cast<const float4*>(sxf);
            float acc = 0.0f;
            #pragma unroll
            for (int k = 0; k < HID4; ++k) {
                const float4 a = Ar[k], v = xf[k];
                acc += a.x*v.x + a.y*v.y + a.z*v.z + a.w*v.w;
            }
            sx[t] = acc;
        }
        __syncthreads();
    }

    if (t == 0) {
        float s = 0.0f;
        for (int k = 0; k < OBS; ++k) s += qacc[k];
        partials[b] = s;
    }
}

// ---------------------------------------------------------------------------
// Phase 3: loss = sum(partials) / (BATCH * SL * HID)
// ---------------------------------------------------------------------------
__global__ void finalize_kernel(const float* __restrict__ partials,
                                float* __restrict__ out)
{
    if (threadIdx.x == 0 && blockIdx.x == 0) {
        float s = 0.0f;
        for (int i = 0; i < BATCH; ++i) s += partials[i];
        out[0] = s * (1.0f / (float)(BATCH * SL * HID));
    }
}

// ---------------------------------------------------------------------------
extern "C" void kernel_launch(void* const* d_in, const int* in_sizes, int n_in,
                              void* d_out, int out_size, void* d_ws, size_t ws_size,
                              hipStream_t stream)
{
    const float* Y = (const float*)d_in[0];   // (32, 3072) f32
    const float* A = (const float*)d_in[1];   // (84, 84)   f32
    const float* C = (const float*)d_in[2];   // (64, 84)   f32
    // d_in[3] = step (unused)

    float* ws = (float*)d_ws;
    float* Kg = ws;                          // SL*HID*OBS = 258048
    float* Wg = Kg + SL*HID*OBS;             // SL*OBS*OBS = 196608
    float* Tg = Wg + SL*OBS*OBS;             // HID*OBS    = 5376
    float* Tt = Tg + HID*OBS;                // OBS*HID    = 5376
    float* Ug = Tt + HID*OBS;                // HID*HID    = 7056
    float* partials = Ug + HID*HID;          // BATCH      = 32
    // total ~472k floats = 1.9 MB of ws

    riccati_kernel<<<1, 512, 0, stream>>>(A, C, Kg, Wg, Tg, Tt, Ug);
    sweep_kernel<<<BATCH, 128, 0, stream>>>(Y, A, C, Kg, Wg, partials);
    finalize_kernel<<<1, 64, 0, stream>>>(partials, (float*)d_out);
}

// Round 2
// 8779.034 us; speedup vs baseline: 1.0918x; 1.0918x over previous
//
#include <hip/hip_runtime.h>

#define SL    48   // sequence length
#define OBS   64   // observation dim
#define HID   84   // hidden dim
#define BATCH 32
#define PTOL  1e-5f   // convergence tol on max|P_{k+1}-P_k| (P entries O(1))

// ---------------------------------------------------------------------------
// 4x4-register-tile NT-GEMM helper: out(i,j) = sum_k X[i][k]*Y[j][k]
// X, Y row-major with row stride == K. All dims multiples of 4.
// ---------------------------------------------------------------------------
template<int K>
__device__ __forceinline__ void tile_nt(const float* __restrict__ X,
                                        const float* __restrict__ Y,
                                        int i0, int j0, float acc[4][4])
{
    #pragma unroll
    for (int k = 0; k < K; k += 4) {
        float4 a[4], b[4];
        #pragma unroll
        for (int r = 0; r < 4; ++r)
            a[r] = *reinterpret_cast<const float4*>(&X[(i0 + r) * K + k]);
        #pragma unroll
        for (int s = 0; s < 4; ++s)
            b[s] = *reinterpret_cast<const float4*>(&Y[(j0 + s) * K + k]);
        #pragma unroll
        for (int r = 0; r < 4; ++r)
            #pragma unroll
            for (int s = 0; s < 4; ++s)
                acc[r][s] += a[r].x * b[s].x + a[r].y * b[s].y
                           + a[r].z * b[s].z + a[r].w * b[s].w;
    }
}

// ---------------------------------------------------------------------------
// Phase 1: Riccati sweep (batch-independent), single block, 512 threads.
// Kalman filter with Q=I, R=0, P_pred_0=I. Emits K_i (and K_i^T), W_i=S_i^-1.
// Adaptive early exit when P converges (geometric, rho(A)~0.46).
// ---------------------------------------------------------------------------
__global__ __launch_bounds__(512)
void riccati_kernel(const float* __restrict__ Ag,   // HID x HID
                    const float* __restrict__ Cg,   // OBS x HID
                    float* __restrict__ Kg,         // SL * HID * OBS
                    float* __restrict__ Ktg,        // SL * OBS * HID (K transposed)
                    float* __restrict__ Wg,         // SL * OBS * OBS
                    float* __restrict__ T2g,        // OBS * HID   (T2 = C*P)
                    float* __restrict__ Tg,         // HID * OBS   (T  = T2^T = P*C^T)
                    float* __restrict__ Ug,         // HID * HID   (U  = A*PF)
                    int*   __restrict__ ncvp)
{
    __shared__ __align__(16) float sP[HID * HID];   // 7056 f (P, symmetric)
    __shared__ __align__(16) float sS[OBS * OBS];   // 4096 f (S -> S^-1)
    __shared__ __align__(16) float rbuf[4 * OBS];   // GJ pivot row-panel copy
    __shared__ __align__(16) float cbuf[OBS * 4];   // GJ pivot col-panel copy
    __shared__ float sRed[8];
    __shared__ int   sFlag;

    const int t = threadIdx.x;

    // P = I
    for (int idx = t; idx < HID * HID; idx += 512)
        sP[idx] = ((idx / HID) == (idx % HID)) ? 1.0f : 0.0f;
    __syncthreads();

    int step;
    for (step = 0; step < SL; ++step) {
        // ---- P1: T2 = C * P  (OBS x HID);  T = T2^T  (HID x OBS)
        // NT(X=C[a][k], Y=P[i][k]) over k<HID. tiles: 16 x 21 = 336
        {
            const int ntl = (OBS / 4) * (HID / 4);
            if (t < ntl) {
                const int a0 = (t / (HID / 4)) * 4, i0 = (t % (HID / 4)) * 4;
                float acc[4][4] = {};
                tile_nt<HID>(Cg, sP, a0, i0, acc);
                #pragma unroll
                for (int r = 0; r < 4; ++r)
                    *reinterpret_cast<float4*>(&T2g[(a0 + r) * HID + i0]) =
                        make_float4(acc[r][0], acc[r][1], acc[r][2], acc[r][3]);
                #pragma unroll
                for (int s = 0; s < 4; ++s)
                    *reinterpret_cast<float4*>(&Tg[(i0 + s) * OBS + a0]) =
                        make_float4(acc[0][s], acc[1][s], acc[2][s], acc[3][s]);
            }
        }
        __syncthreads();

        // ---- P2: S = C * T = NT(X=C, Y=T2) over k<HID. tiles 16x16 = 256
        {
            const int ntl = (OBS / 4) * (OBS / 4);
            if (t < ntl) {
                const int a0 = (t / (OBS / 4)) * 4, b0 = (t % (OBS / 4)) * 4;
                float acc[4][4] = {};
                tile_nt<HID>(Cg, T2g, a0, b0, acc);
                #pragma unroll
                for (int r = 0; r < 4; ++r)
                    #pragma unroll
                    for (int s = 0; s < 4; ++s)
                        sS[(a0 + r) * OBS + b0 + s] = acc[r][s];
            }
        }
        __syncthreads();

        // ---- P3: in-place block Gauss-Jordan inverse of sS (SPD), b=4
        for (int g = 0; g < OBS / 4; ++g) {
            const int p0 = g * 4;
            // Phase A: copy pivot row-panel and col-panel
            if (t < 256) {
                const int r = t / OBS, j = t % OBS;
                rbuf[r * OBS + j] = sS[(p0 + r) * OBS + j];
            } else if (t < 512) {
                const int u = t - 256, i = u / 4, l = u % 4;
                cbuf[i * 4 + l] = sS[i * OBS + p0 + l];
            }
            __syncthreads();
            // Phase B: replicated 4x4 pivot inverse + full update (8 elems/thread)
            {
                float m[4][4], dinv[4][4];
                #pragma unroll
                for (int r = 0; r < 4; ++r)
                    #pragma unroll
                    for (int c = 0; c < 4; ++c) {
                        m[r][c] = rbuf[r * OBS + p0 + c];
                        dinv[r][c] = (r == c) ? 1.0f : 0.0f;
                    }
                #pragma unroll
                for (int p = 0; p < 4; ++p) {
                    const float f = 1.0f / m[p][p];
                    #pragma unroll
                    for (int c = 0; c < 4; ++c) { m[p][c] *= f; dinv[p][c] *= f; }
                    #pragma unroll
                    for (int r = 0; r < 4; ++r) {
                        if (r == p) continue;
                        const float gg = m[r][p];
                        #pragma unroll
                        for (int c = 0; c < 4; ++c) {
                            m[r][c]    -= gg * m[p][c];
                            dinv[r][c] -= gg * dinv[p][c];
                        }
                    }
                }
                const int i = t / 8, j0 = (t % 8) * 8;
                const bool ipiv = (i >= p0) && (i < p0 + 4);
                float e4[4] = {0.f, 0.f, 0.f, 0.f};
                if (!ipiv) {
                    #pragma unroll
                    for (int c = 0; c < 4; ++c) {
                        float s = 0.f;
                        #pragma unroll
                        for (int l = 0; l < 4; ++l) s += cbuf[i * 4 + l] * dinv[l][c];
                        e4[c] = s;
                    }
                }
                #pragma unroll
                for (int jj = 0; jj < 8; ++jj) {
                    const int j = j0 + jj;
                    const bool jpiv = (j >= p0) && (j < p0 + 4);
                    float val;
                    if (ipiv) {
                        const int r = i - p0;
                        if (jpiv) val = dinv[r][j - p0];
                        else {
                            float s = 0.f;
                            #pragma unroll
                            for (int c = 0; c < 4; ++c) s += dinv[r][c] * rbuf[c * OBS + j];
                            val = s;
                        }
                    } else if (jpiv) {
                        val = -e4[j - p0];
                    } else {
                        val = sS[i * OBS + j] - (e4[0] * rbuf[j]
                              + e4[1] * rbuf[OBS + j]
                              + e4[2] * rbuf[2 * OBS + j]
                              + e4[3] * rbuf[3 * OBS + j]);
                    }
                    sS[i * OBS + j] = val;
                }
            }
            __syncthreads();
        }

        // ---- P4: K = T * W = NT(X=T, Y=W(sym)) over k<OBS. tiles 21x16 = 336
        //          store Kg (row) + Ktg (transposed); also stream W out.
        {
            float* Kstep  = Kg  + step * HID * OBS;
            float* Ktstep = Ktg + step * OBS * HID;
            float* Wstep  = Wg  + step * OBS * OBS;
            const int ntl = (HID / 4) * (OBS / 4);
            if (t < ntl) {
                const int i0 = (t / (OBS / 4)) * 4, j0 = (t % (OBS / 4)) * 4;
                float acc[4][4] = {};
                tile_nt<OBS>(Tg, sS, i0, j0, acc);
                #pragma unroll
                for (int r = 0; r < 4; ++r)
                    *reinterpret_cast<float4*>(&Kstep[(i0 + r) * OBS + j0]) =
                        make_float4(acc[r][0], acc[r][1], acc[r][2], acc[r][3]);
                #pragma unroll
                for (int s = 0; s < 4; ++s)
                    *reinterpret_cast<float4*>(&Ktstep[(j0 + s) * HID + i0]) =
                        make_float4(acc[0][s], acc[1][s], acc[2][s], acc[3][s]);
            }
            for (int idx = t; idx < (OBS * OBS) / 4; idx += 512)
                reinterpret_cast<float4*>(Wstep)[idx] =
                    reinterpret_cast<const float4*>(sS)[idx];
        }
        __syncthreads();

        // ---- P5: PF = P - K*T^T  = P - NT(X=T, Y=K) (symmetric). k<OBS. 441 tiles
        {
            const float* Kstep = Kg + step * HID * OBS;
            const int ntl = (HID / 4) * (HID / 4);
            if (t < ntl) {
                const int i0 = (t / (HID / 4)) * 4, j0 = (t % (HID / 4)) * 4;
                float acc[4][4] = {};
                tile_nt<OBS>(Tg, Kstep, i0, j0, acc);
                #pragma unroll
                for (int r = 0; r < 4; ++r)
                    #pragma unroll
                    for (int s = 0; s < 4; ++s)
                        sP[(i0 + r) * HID + j0 + s] -= acc[r][s];
            }
        }
        __syncthreads();

        // ---- P6: U = A * PF = NT(X=A, Y=PF(sym)). k<HID. 441 tiles
        {
            const int ntl = (HID / 4) * (HID / 4);
            if (t < ntl) {
                const int i0 = (t / (HID / 4)) * 4, j0 = (t % (HID / 4)) * 4;
                float acc[4][4] = {};
                tile_nt<HID>(Ag, sP, i0, j0, acc);
                #pragma unroll
                for (int r = 0; r < 4; ++r)
                    *reinterpret_cast<float4*>(&Ug[(i0 + r) * HID + j0]) =
                        make_float4(acc[r][0], acc[r][1], acc[r][2], acc[r][3]);
            }
        }
        __syncthreads();

        // ---- P7: Pnew = A*U^T + I = NT(X=A, Y=U) + I (symmetric). diff-tracked
        float maxd = 0.f;
        {
            const int ntl = (HID / 4) * (HID / 4);
            if (t < ntl) {
                const int i0 = (t / (HID / 4)) * 4, j0 = (t % (HID / 4)) * 4;
                float acc[4][4] = {};
                tile_nt<HID>(Ag, Ug, i0, j0, acc);
                #pragma unroll
                for (int r = 0; r < 4; ++r)
                    #pragma unroll
                    for (int s = 0; s < 4; ++s) {
                        float v = acc[r][s] + (((i0 + r) == (j0 + s)) ? 1.0f : 0.0f);
                        const int idx = (i0 + r) * HID + j0 + s;
                        const float d = fabsf(v - sP[idx]);
                        maxd = fmaxf(maxd, d);
                        sP[idx] = v;
                    }
            }
        }
        // ---- P8: convergence reduction
        #pragma unroll
        for (int m = 32; m >= 1; m >>= 1)
            maxd = fmaxf(maxd, __shfl_xor(maxd, m));
        if ((t & 63) == 0) sRed[t >> 6] = maxd;
        __syncthreads();
        if (t == 0) {
            float mm = 0.f;
            #pragma unroll
            for (int w = 0; w < 8; ++w) mm = fmaxf(mm, sRed[w]);
            sFlag = (mm < PTOL) ? 1 : 0;
        }
        __syncthreads();
        if (sFlag) { ++step; break; }
    }

    if (t == 0) *ncvp = (step < SL) ? step : SL;
}

// ---------------------------------------------------------------------------
// Phase 2: per-batch Kalman sweep, q_b = sum_i e_i^T W_i e_i (32 blocks x 128)
// ---------------------------------------------------------------------------
__global__ __launch_bounds__(128)
void sweep_kernel(const float* __restrict__ Y,     // BATCH x (SL*OBS)
                  const float* __restrict__ Ag,
                  const float* __restrict__ Cg,
                  const float* __restrict__ Ktg,   // SL * OBS * HID
                  const float* __restrict__ Wg,    // SL * OBS * OBS
                  const int*   __restrict__ ncvp,
                  float* __restrict__ partials)
{
    __shared__ float sAt[HID * HID];  // sAt[k*HID+i] = A[i][k]
    __shared__ float sCt[HID * OBS];  // sCt[k*OBS+a] = C[a][k]
    __shared__ float sx[HID];
    __shared__ float sxf[HID];
    __shared__ float se[OBS];

    const int b = blockIdx.x;
    const int t = threadIdx.x;
    const float* y = &Y[b * SL * OBS];

    for (int idx = t; idx < HID * HID; idx += 128) {
        const int i = idx / HID, k = idx % HID;
        sAt[k * HID + i] = Ag[idx];
    }
    for (int idx = t; idx < OBS * HID; idx += 128) {
        const int a = idx / HID, k = idx % HID;
        sCt[k * OBS + a] = Cg[idx];
    }
    if (t < HID) sx[t] = 0.0f;
    __syncthreads();

    const int ncv = *ncvp;
    float q = 0.0f;

    for (int i = 0; i < SL; ++i) {
        const int s = (i < ncv) ? i : (ncv - 1);
        const float* Ws = Wg  + s * OBS * OBS;
        const float* Ks = Ktg + s * OBS * HID;

        // e = y_i - C x
        if (t < OBS) {
            float acc = 0.f;
            #pragma unroll
            for (int k = 0; k < HID; ++k) acc += sCt[k * OBS + t] * sx[k];
            se[t] = y[i * OBS + t] - acc;
        }
        __syncthreads();

        // q += e^T W e   (W symmetric: read column t, coalesced)
        if (t < OBS) {
            float wacc = 0.f;
            #pragma unroll
            for (int k = 0; k < OBS; ++k) wacc += Ws[k * OBS + t] * se[k];
            q += se[t] * wacc;
        }
        // xf = x + K e   (K transposed layout: coalesced)
        if (t < HID) {
            float kacc = 0.f;
            #pragma unroll
            for (int m = 0; m < OBS; ++m) kacc += Ks[m * HID + t] * se[m];
            sxf[t] = sx[t] + kacc;
        }
        __syncthreads();

        // x = A xf
        if (t < HID) {
            float acc = 0.f;
            #pragma unroll
            for (int k = 0; k < HID; ++k) acc += sAt[k * HID + t] * sxf[k];
            sx[t] = acc;
        }
        __syncthreads();
    }

    // reduce q over wave 0 (threads 0..63 hold contributions)
    #pragma unroll
    for (int m = 32; m >= 1; m >>= 1)
        q += __shfl_xor(q, m);
    if (t == 0) partials[b] = q;
}

// ---------------------------------------------------------------------------
// Phase 3: loss = sum(partials) / (BATCH*SL*HID)
// ---------------------------------------------------------------------------
__global__ void finalize_kernel(const float* __restrict__ partials,
                                float* __restrict__ out)
{
    const int t = threadIdx.x;
    float q = (t < BATCH) ? partials[t] : 0.0f;
    #pragma unroll
    for (int m = 32; m >= 1; m >>= 1)
        q += __shfl_xor(q, m);
    if (t == 0) out[0] = q * (1.0f / (float)(BATCH * SL * HID));
}

// ---------------------------------------------------------------------------
extern "C" void kernel_launch(void* const* d_in, const int* in_sizes, int n_in,
                              void* d_out, int out_size, void* d_ws, size_t ws_size,
                              hipStream_t stream)
{
    const float* Y = (const float*)d_in[0];   // (32, 3072) f32
    const float* A = (const float*)d_in[1];   // (84, 84)   f32
    const float* C = (const float*)d_in[2];   // (64, 84)   f32
    // d_in[3] = step (unused)

    float* ws = (float*)d_ws;
    float* Kg   = ws;                                  // 48*84*64 = 258048
    float* Ktg  = Kg   + SL * HID * OBS;               // 48*64*84 = 258048
    float* Wg   = Ktg  + SL * OBS * HID;               // 48*64*64 = 196608
    float* T2g  = Wg   + SL * OBS * OBS;               // 64*84 = 5376
    float* Tg   = T2g  + OBS * HID;                    // 84*64 = 5376
    float* Ug   = Tg   + HID * OBS;                    // 84*84 = 7056
    float* partials = Ug + HID * HID;                  // 32
    int*   ncvp = (int*)(partials + BATCH);            // 1
    // total ~2.93 MB of ws

    riccati_kernel<<<1, 512, 0, stream>>>(A, C, Kg, Ktg, Wg, T2g, Tg, Ug, ncvp);
    sweep_kernel<<<BATCH, 128, 0, stream>>>(Y, A, C, Ktg, Wg, ncvp, partials);
    finalize_kernel<<<1, 64, 0, stream>>>(partials, (float*)d_out);
}

// Round 3
// 431.517 us; speedup vs baseline: 22.2114x; 20.3446x over previous
//
#include <hip/hip_runtime.h>

#define SL    48   // sequence length
#define OBS   64   // observation dim
#define HID   84   // hidden dim
#define BATCH 32
#define PTOL  1e-4f  // tol on max|dW|,|dK| between consecutive steps

// LDS layout (floats). All offsets 16B-aligned.
#define OFF_P   0                  // 84 x 96  (stride 96 = 24 chunks, 21 logical)
#define OFF_T2  8064               // 64 x 96
#define OFF_T   14208              // 84 x 64  (16 chunks)
#define OFF_U   8064               // 84 x 96  (aliases T2+T region; disjoint lifetime)
#define OFF_S   19584              // 64 x 64
#define OFF_K   23680              // 84 x 64
#define OFF_RB  29056              // 4 x 64 pivot row panel
#define OFF_CB  29312              // 64 x 4 pivot col panel
#define OFF_RED 29568              // 8
#define SMEM_F  29576
#define SMEM_BYTES (SMEM_F * 4)

__device__ __forceinline__ int swz(int row, int c) { return c ^ ((row >> 2) & 7); }

// NT-GEMM 4x4 tile: acc[r][s] += sum_k X[i0+r][k] * Y[j0+s][k], k = 4*KC values.
// XS/YS = row strides (floats). XSW/YSW: operand stored with chunk swizzle.
template<int KC, int XS, bool XSW, int YS, bool YSW>
__device__ __forceinline__ void tile_nt(const float* __restrict__ X,
                                        const float* __restrict__ Y,
                                        int i0, int j0, float acc[4][4])
{
    const int xk = XSW ? ((i0 >> 2) & 7) : 0;
    const int yk = YSW ? ((j0 >> 2) & 7) : 0;
    #pragma unroll 4
    for (int c = 0; c < KC; ++c) {
        const int xc = (XSW ? (c ^ xk) : c) << 2;
        const int yc = (YSW ? (c ^ yk) : c) << 2;
        float4 a[4], b[4];
        #pragma unroll
        for (int r = 0; r < 4; ++r)
            a[r] = *reinterpret_cast<const float4*>(&X[(i0 + r) * XS + xc]);
        #pragma unroll
        for (int s = 0; s < 4; ++s)
            b[s] = *reinterpret_cast<const float4*>(&Y[(j0 + s) * YS + yc]);
        #pragma unroll
        for (int r = 0; r < 4; ++r)
            #pragma unroll
            for (int s = 0; s < 4; ++s)
                acc[r][s] += a[r].x * b[s].x + a[r].y * b[s].y
                           + a[r].z * b[s].z + a[r].w * b[s].w;
    }
}

// ---------------------------------------------------------------------------
// Phase 1: Riccati sweep, single block, 512 threads, all-LDS working set.
// Emits per step: K^T (OBS x HID) and W = S^{-1} (OBS x OBS) to global.
// Early-exits when max|dW|,|dK| < PTOL (the quantities phase 2 consumes).
// ---------------------------------------------------------------------------
__global__ __launch_bounds__(512)
void riccati_kernel(const float* __restrict__ Ag,   // HID x HID
                    const float* __restrict__ Cg,   // OBS x HID
                    float* __restrict__ Ktg,        // SL * OBS * HID
                    float* __restrict__ Wg,         // SL * OBS * OBS
                    int*   __restrict__ ncvp)
{
    extern __shared__ float smem[];
    float*  sP   = smem + OFF_P;
    float*  sT2  = smem + OFF_T2;
    float*  sT   = smem + OFF_T;
    float*  sU   = smem + OFF_U;
    float*  sS   = smem + OFF_S;
    float*  sK   = smem + OFF_K;
    float*  rbuf = smem + OFF_RB;
    float*  cbuf = smem + OFF_CB;
    float*  sRed = smem + OFF_RED;
    float4* sP4  = reinterpret_cast<float4*>(sP);
    float4* sT24 = reinterpret_cast<float4*>(sT2);
    float4* sT4  = reinterpret_cast<float4*>(sT);
    float4* sU4  = reinterpret_cast<float4*>(sU);
    float4* sS4  = reinterpret_cast<float4*>(sS);
    float4* sK4  = reinterpret_cast<float4*>(sK);

    const int t = threadIdx.x;

    // ---- P = I (write every physical chunk once; pad chunks zeroed)
    for (int u = t; u < HID * 24; u += 512) {
        const int row = u / 24, pc = u % 24;
        const int lc = pc ^ ((row >> 2) & 7);
        float4 v = make_float4(0.f, 0.f, 0.f, 0.f);
        if (lc < 21) {
            const int base = lc * 4;
            if (row == base)     v.x = 1.f;
            if (row == base + 1) v.y = 1.f;
            if (row == base + 2) v.z = 1.f;
            if (row == base + 3) v.w = 1.f;
        }
        sP4[row * 24 + pc] = v;
    }
    __syncthreads();

    int ncv = SL;
    for (int step = 0; step < SL; ++step) {
        // ---- P1: T2 = C * P (OBS x HID); T = T2^T (HID x OBS)
        if (t < 336) {
            const int a0 = (t / 21) * 4, i0 = (t % 21) * 4;
            float acc[4][4] = {};
            tile_nt<21, HID, false, 96, true>(Cg, sP, a0, i0, acc);
            #pragma unroll
            for (int r = 0; r < 4; ++r)
                sT24[(a0 + r) * 24 + swz(a0 + r, i0 >> 2)] =
                    make_float4(acc[r][0], acc[r][1], acc[r][2], acc[r][3]);
            #pragma unroll
            for (int s = 0; s < 4; ++s)
                sT4[(i0 + s) * 16 + swz(i0 + s, a0 >> 2)] =
                    make_float4(acc[0][s], acc[1][s], acc[2][s], acc[3][s]);
        }
        __syncthreads();

        // ---- P2: S = T2 * C^T (OBS x OBS)
        if (t < 256) {
            const int a0 = (t / 16) * 4, b0 = (t % 16) * 4;
            float acc[4][4] = {};
            tile_nt<21, 96, true, HID, false>(sT2, Cg, a0, b0, acc);
            #pragma unroll
            for (int r = 0; r < 4; ++r)
                sS4[(a0 + r) * 16 + swz(a0 + r, b0 >> 2)] =
                    make_float4(acc[r][0], acc[r][1], acc[r][2], acc[r][3]);
        }
        __syncthreads();

        // ---- P3: in-place block Gauss-Jordan inverse of S (SPD), block 4
        for (int g = 0; g < 16; ++g) {
            const int p0 = g * 4;
            // Phase A: snapshot pivot row-panel (logical) and col-panel
            if (t < 64) {
                const int r = t >> 4, c = t & 15;
                reinterpret_cast<float4*>(rbuf)[r * 16 + c] =
                    sS4[(p0 + r) * 16 + swz(p0 + r, c)];
            } else if (t < 128) {
                const int row = t - 64;
                reinterpret_cast<float4*>(cbuf)[row] = sS4[row * 16 + swz(row, g)];
            }
            __syncthreads();
            // replicated 4x4 pivot-block inverse
            float m[4][4], dinv[4][4];
            #pragma unroll
            for (int r = 0; r < 4; ++r)
                #pragma unroll
                for (int c = 0; c < 4; ++c) {
                    m[r][c] = rbuf[r * 64 + p0 + c];
                    dinv[r][c] = (r == c) ? 1.0f : 0.0f;
                }
            #pragma unroll
            for (int p = 0; p < 4; ++p) {
                const float f = 1.0f / m[p][p];
                #pragma unroll
                for (int c = 0; c < 4; ++c) { m[p][c] *= f; dinv[p][c] *= f; }
                #pragma unroll
                for (int r = 0; r < 4; ++r) {
                    if (r == p) continue;
                    const float gg = m[r][p];
                    #pragma unroll
                    for (int c = 0; c < 4; ++c) {
                        m[r][c]    -= gg * m[p][c];
                        dinv[r][c] -= gg * dinv[p][c];
                    }
                }
            }
            // Phase B: each thread owns 2 (row, chunk) cells; no cross-ownership reads
            #pragma unroll
            for (int rep = 0; rep < 2; ++rep) {
                const int u = t + rep * 512;
                const int i = u >> 4, c = u & 15;
                float o[4];
                if (i >= p0 && i < p0 + 4) {
                    const int r = i - p0;
                    if (c == g) {
                        o[0] = dinv[r][0]; o[1] = dinv[r][1];
                        o[2] = dinv[r][2]; o[3] = dinv[r][3];
                    } else {
                        #pragma unroll
                        for (int j = 0; j < 4; ++j) {
                            float s = 0.f;
                            #pragma unroll
                            for (int l = 0; l < 4; ++l)
                                s += dinv[r][l] * rbuf[l * 64 + 4 * c + j];
                            o[j] = s;
                        }
                    }
                } else {
                    float e[4];
                    #pragma unroll
                    for (int l = 0; l < 4; ++l) {
                        float s = 0.f;
                        #pragma unroll
                        for (int mm = 0; mm < 4; ++mm)
                            s += cbuf[i * 4 + mm] * dinv[mm][l];
                        e[l] = s;
                    }
                    if (c == g) {
                        o[0] = -e[0]; o[1] = -e[1]; o[2] = -e[2]; o[3] = -e[3];
                    } else {
                        const float4 old = sS4[i * 16 + swz(i, c)];
                        o[0] = old.x; o[1] = old.y; o[2] = old.z; o[3] = old.w;
                        #pragma unroll
                        for (int l = 0; l < 4; ++l) {
                            const float el = e[l];
                            #pragma unroll
                            for (int j = 0; j < 4; ++j)
                                o[j] -= el * rbuf[l * 64 + 4 * c + j];
                        }
                    }
                }
                sS4[i * 16 + swz(i, c)] = make_float4(o[0], o[1], o[2], o[3]);
            }
            __syncthreads();
        }

        // ---- P4: K = T * W (HID x OBS) -> sK + Ktg; stream W -> Wg; convergence
        float maxd = 0.0f;
        float* Ktstep = Ktg + step * OBS * HID;
        const float* Ktprev = Ktg + (step - 1) * OBS * HID;
        if (t < 336) {
            const int i0 = (t / 16) * 4, j0 = (t % 16) * 4;
            float acc[4][4] = {};
            tile_nt<16, 64, true, 64, true>(sT, sS, i0, j0, acc);
            #pragma unroll
            for (int r = 0; r < 4; ++r)
                sK4[(i0 + r) * 16 + swz(i0 + r, j0 >> 2)] =
                    make_float4(acc[r][0], acc[r][1], acc[r][2], acc[r][3]);
            #pragma unroll
            for (int s = 0; s < 4; ++s) {
                const float4 nv = make_float4(acc[0][s], acc[1][s], acc[2][s], acc[3][s]);
                float4* dst = reinterpret_cast<float4*>(&Ktstep[(j0 + s) * HID + i0]);
                if (step > 0) {
                    const float4 ov =
                        *reinterpret_cast<const float4*>(&Ktprev[(j0 + s) * HID + i0]);
                    maxd = fmaxf(maxd, fmaxf(fmaxf(fabsf(nv.x - ov.x), fabsf(nv.y - ov.y)),
                                             fmaxf(fabsf(nv.z - ov.z), fabsf(nv.w - ov.w))));
                }
                *dst = nv;
            }
        }
        {
            float* Wstep = Wg + step * OBS * OBS;
            const float* Wprev = Wg + (step - 1) * OBS * OBS;
            #pragma unroll
            for (int rep = 0; rep < 2; ++rep) {
                const int u = t + rep * 512;
                const int row = u >> 4, c = u & 15;
                const float4 nv = sS4[row * 16 + swz(row, c)];
                if (step > 0) {
                    const float4 ov = reinterpret_cast<const float4*>(Wprev)[row * 16 + c];
                    maxd = fmaxf(maxd, fmaxf(fmaxf(fabsf(nv.x - ov.x), fabsf(nv.y - ov.y)),
                                             fmaxf(fabsf(nv.z - ov.z), fabsf(nv.w - ov.w))));
                }
                reinterpret_cast<float4*>(Wstep)[row * 16 + c] = nv;
            }
        }
        #pragma unroll
        for (int mo = 32; mo >= 1; mo >>= 1)
            maxd = fmaxf(maxd, __shfl_xor(maxd, mo));
        if ((t & 63) == 0) sRed[t >> 6] = maxd;
        __syncthreads();
        float mm = sRed[0];
        #pragma unroll
        for (int w = 1; w < 8; ++w) mm = fmaxf(mm, sRed[w]);
        if (step > 0 && mm < PTOL) { ncv = step + 1; break; }
        if (step == SL - 1) break;   // last step: next-P unneeded

        // ---- P5: PF = P - K * T^T (in place on sP)
        if (t < 441) {
            const int i0 = (t / 21) * 4, j0 = (t % 21) * 4;
            float acc[4][4] = {};
            tile_nt<16, 64, true, 64, true>(sK, sT, i0, j0, acc);
            #pragma unroll
            for (int r = 0; r < 4; ++r) {
                float4* p = &sP4[(i0 + r) * 24 + swz(i0 + r, j0 >> 2)];
                float4 v = *p;
                v.x -= acc[r][0]; v.y -= acc[r][1]; v.z -= acc[r][2]; v.w -= acc[r][3];
                *p = v;
            }
        }
        __syncthreads();

        // ---- P6: U = A * PF (PF symmetric -> NT form)   [U aliases T2/T]
        if (t < 441) {
            const int i0 = (t / 21) * 4, j0 = (t % 21) * 4;
            float acc[4][4] = {};
            tile_nt<21, HID, false, 96, true>(Ag, sP, i0, j0, acc);
            #pragma unroll
            for (int r = 0; r < 4; ++r)
                sU4[(i0 + r) * 24 + swz(i0 + r, j0 >> 2)] =
                    make_float4(acc[r][0], acc[r][1], acc[r][2], acc[r][3]);
        }
        __syncthreads();

        // ---- P7: P = A * U^T + I
        if (t < 441) {
            const int i0 = (t / 21) * 4, j0 = (t % 21) * 4;
            float acc[4][4] = {};
            tile_nt<21, HID, false, 96, true>(Ag, sU, i0, j0, acc);
            #pragma unroll
            for (int r = 0; r < 4; ++r) {
                float4 v = make_float4(acc[r][0], acc[r][1], acc[r][2], acc[r][3]);
                if (i0 + r == j0 + 0) v.x += 1.f;
                if (i0 + r == j0 + 1) v.y += 1.f;
                if (i0 + r == j0 + 2) v.z += 1.f;
                if (i0 + r == j0 + 3) v.w += 1.f;
                sP4[(i0 + r) * 24 + swz(i0 + r, j0 >> 2)] = v;
            }
        }
        __syncthreads();
    }

    if (t == 0) *ncvp = ncv;
}

// ---------------------------------------------------------------------------
// Phase 2: per-batch Kalman sweep, q_b = sum_i e_i^T W_i e_i (32 blocks x 128)
// ---------------------------------------------------------------------------
__global__ __launch_bounds__(128)
void sweep_kernel(const float* __restrict__ Y,     // BATCH x (SL*OBS)
                  const float* __restrict__ Ag,
                  const float* __restrict__ Cg,
                  const float* __restrict__ Ktg,   // SL * OBS * HID
                  const float* __restrict__ Wg,    // SL * OBS * OBS
                  const int*   __restrict__ ncvp,
                  float* __restrict__ partials)
{
    __shared__ float sAt[HID * HID];  // sAt[k*HID+i] = A[i][k]
    __shared__ float sCt[HID * OBS];  // sCt[k*OBS+a] = C[a][k]
    __shared__ float sx[HID];
    __shared__ float sxf[HID];
    __shared__ float se[OBS];

    const int b = blockIdx.x;
    const int t = threadIdx.x;
    const float* y = &Y[b * SL * OBS];

    for (int idx = t; idx < HID * HID; idx += 128) {
        const int i = idx / HID, k = idx % HID;
        sAt[k * HID + i] = Ag[idx];
    }
    for (int idx = t; idx < OBS * HID; idx += 128) {
        const int a = idx / HID, k = idx % HID;
        sCt[k * OBS + a] = Cg[idx];
    }
    if (t < HID) sx[t] = 0.0f;
    __syncthreads();

    const int ncv = *ncvp;
    float q = 0.0f;

    for (int i = 0; i < SL; ++i) {
        const int s = (i < ncv) ? i : (ncv - 1);
        const float* Ws = Wg  + s * OBS * OBS;
        const float* Ks = Ktg + s * OBS * HID;

        if (t < OBS) {
            float acc = 0.f;
            #pragma unroll
            for (int k = 0; k < HID; ++k) acc += sCt[k * OBS + t] * sx[k];
            se[t] = y[i * OBS + t] - acc;
        }
        __syncthreads();

        if (t < OBS) {
            float wacc = 0.f;
            #pragma unroll
            for (int k = 0; k < OBS; ++k) wacc += Ws[k * OBS + t] * se[k];
            q += se[t] * wacc;
        }
        if (t < HID) {
            float kacc = 0.f;
            #pragma unroll
            for (int m = 0; m < OBS; ++m) kacc += Ks[m * HID + t] * se[m];
            sxf[t] = sx[t] + kacc;
        }
        __syncthreads();

        if (t < HID) {
            float acc = 0.f;
            #pragma unroll
            for (int k = 0; k < HID; ++k) acc += sAt[k * HID + t] * sxf[k];
            sx[t] = acc;
        }
        __syncthreads();
    }

    #pragma unroll
    for (int m = 32; m >= 1; m >>= 1)
        q += __shfl_xor(q, m);
    if (t == 0) partials[b] = q;
}

// ---------------------------------------------------------------------------
__global__ void finalize_kernel(const float* __restrict__ partials,
                                float* __restrict__ out)
{
    const int t = threadIdx.x;
    float q = (t < BATCH) ? partials[t] : 0.0f;
    #pragma unroll
    for (int m = 32; m >= 1; m >>= 1)
        q += __shfl_xor(q, m);
    if (t == 0) out[0] = q * (1.0f / (float)(BATCH * SL * HID));
}

// ---------------------------------------------------------------------------
extern "C" void kernel_launch(void* const* d_in, const int* in_sizes, int n_in,
                              void* d_out, int out_size, void* d_ws, size_t ws_size,
                              hipStream_t stream)
{
    const float* Y = (const float*)d_in[0];   // (32, 3072) f32
    const float* A = (const float*)d_in[1];   // (84, 84)   f32
    const float* C = (const float*)d_in[2];   // (64, 84)   f32
    // d_in[3] = step (unused)

    float* ws = (float*)d_ws;
    float* Ktg = ws;                           // SL*OBS*HID = 258048
    float* Wg  = Ktg + SL * OBS * HID;         // SL*OBS*OBS = 196608
    float* partials = Wg + SL * OBS * OBS;     // 32
    int*   ncvp = (int*)(partials + BATCH);    // 1

    (void)hipFuncSetAttribute((const void*)riccati_kernel,
                              hipFuncAttributeMaxDynamicSharedMemorySize,
                              SMEM_BYTES);

    riccati_kernel<<<1, 512, SMEM_BYTES, stream>>>(A, C, Ktg, Wg, ncvp);
    sweep_kernel<<<BATCH, 128, 0, stream>>>(Y, A, C, Ktg, Wg, ncvp, partials);
    finalize_kernel<<<1, 64, 0, stream>>>(partials, (float*)d_out);
}